// Round 7
// baseline (244.674 us; speedup 1.0000x reference)
//
#include <hip/hip_runtime.h>

#define F 128
#define TILE 16
#define NTHR 512
#define NBLK 512

typedef __attribute__((ext_vector_type(8))) __bf16 bf16x8;
typedef __attribute__((ext_vector_type(4))) float f32x4;
typedef __attribute__((ext_vector_type(8))) unsigned short us8;
typedef __attribute__((ext_vector_type(4))) unsigned short us4;
typedef __attribute__((ext_vector_type(2))) unsigned short us2;

struct f3 { float x, y, z; };   // 12B -> global_store_dwordx3

__device__ __forceinline__ unsigned short f2bf(float x) {
    __bf16 h = (__bf16)x;                       // HW v_cvt (RNE)
    return __builtin_bit_cast(unsigned short, h);
}
__device__ __forceinline__ float bf2f(unsigned short u) {
    unsigned x = ((unsigned)u) << 16;
    return __builtin_bit_cast(float, x);
}
__device__ __forceinline__ bf16x8 pack8(float4 a, float4 b) {
    us8 t;
    t[0] = f2bf(a.x); t[1] = f2bf(a.y); t[2] = f2bf(a.z); t[3] = f2bf(a.w);
    t[4] = f2bf(b.x); t[5] = f2bf(b.y); t[6] = f2bf(b.z); t[7] = f2bf(b.w);
    return __builtin_bit_cast(bf16x8, t);
}

// async global->LDS, 16B per lane; lds base wave-uniform
__device__ __forceinline__ void gload16(const float* g, const unsigned short* l) {
    __builtin_amdgcn_global_load_lds(
        (const __attribute__((address_space(1))) void*)g,
        (__attribute__((address_space(3))) void*)l, 16, 0, 0);
}

// LDS map (ushort units), 25216 sh = 50432 B -> 2 blocks/CU with margin
#define RAWV 0        // 12288 sh : raw f32 v tile (16x128x3), linear
#define A1B  12288    // 48 x 136 : v bf16, row m = c*16+nl
#define A1S  136
#define A2B  18816    // 16 x 264 : s bf16 | ||Vv||^2 bf16
#define A2S  264
#define A3B  23040    // 16 x 136 : h bf16
#define A3S  136
#define SHSZ 25216

__global__ __launch_bounds__(256)
void prep_w(const float* __restrict__ Uw, const float* __restrict__ Vw,
            const float* __restrict__ aw1, const float* __restrict__ aw2,
            unsigned short* __restrict__ wbf)
{
    int i = (blockIdx.x * 256 + threadIdx.x) * 4;   // grid 112x256 covers 114688
    const float* src; int off;
    if (i < 16384)      { src = Uw;  off = i; }
    else if (i < 32768) { src = Vw;  off = i - 16384; }
    else if (i < 65536) { src = aw1; off = i - 32768; }
    else                { src = aw2; off = i - 65536; }
    float4 x = *(const float4*)&src[off];
    us4 o;
    o[0] = f2bf(x.x); o[1] = f2bf(x.y); o[2] = f2bf(x.z); o[3] = f2bf(x.w);
    *(us4*)&wbf[i] = o;
}

template<bool PRE>
__global__ __launch_bounds__(NTHR) __attribute__((amdgpu_waves_per_eu(4)))
void painn_main(const float* __restrict__ s, const float* __restrict__ v,
                const float* __restrict__ Uw, const float* __restrict__ Vw,
                const float* __restrict__ aw1, const float* __restrict__ ab1,
                const float* __restrict__ aw2, const float* __restrict__ ab2,
                const unsigned short* __restrict__ wbf,
                float* __restrict__ out, int Ntot)
{
    __shared__ __align__(16) unsigned short SH[SHSZ];

    const int tid  = threadIdx.x;
    const int lane = tid & 63;
    const int w    = tid >> 6;        // wave 0..7
    const int l15  = lane & 15;
    const int kp   = lane >> 4;       // 0..3
    const int col  = (w << 4) | l15;  // output column 0..127
    const size_t NF = (size_t)Ntot * F;
    const int NT   = Ntot / TILE;     // 100000/16 = 6250 exact

    const unsigned short* wU  = wbf;
    const unsigned short* wV  = wbf + 16384;
    const unsigned short* wW1 = wbf + 32768;
    const unsigned short* wW2 = wbf + 65536;

    const float b1  = ab1[col];
    const float bss = ab2[col];
    const float bsv = ab2[F + col];
    const float bvv = ab2[2 * F + col];

    const int srow = tid >> 5;           // s row 0..15
    const int sf0  = (tid & 31) << 2;    // s f-offset (4 floats)

    const float* rawv = (const float*)&SH[RAWV];

    float4 sreg;   // s for current tile (loaded one iteration ahead)

    // ---- prologue: asyncs + s for first tile ----
    {
        int t0 = blockIdx.x;
        const float* vsrc = v + (size_t)t0 * TILE * 384;
        #pragma unroll
        for (int j = 0; j < 3; ++j) {
            int ofs = (w + j * 8) * 256;               // floats; 1024B per wave-round
            gload16(vsrc + ofs + lane * 4, &SH[RAWV + ofs * 2]);
        }
        sreg = *(const float4*)(s + (size_t)t0 * TILE * 128 + srow * 128 + sf0);
    }

    for (int t = blockIdx.x; t < NT; t += NBLK) {
        // top: own asyncs + sreg arrived (tolerate up to 8 outstanding stores)
        asm volatile("s_waitcnt vmcnt(8)" ::: "memory");
        __builtin_amdgcn_s_barrier();                        // B0: raw(t) complete

        // ---- convert: raw f32 -> A1 (v bf16, c-major); sreg -> A2 s-half ----
        #pragma unroll
        for (int it = 0; it < 2; ++it) {
            int idx = tid + it * 512;         // 1024 tasks: 16 rows x 64 f-pairs
            int nl  = idx >> 6;
            int f0  = (idx & 63) << 1;
            const float2* src = (const float2*)&rawv[nl * 384 + f0 * 3];
            float2 ab = src[0], cd = src[1], ef = src[2];
            us2 p;
            p[0] = f2bf(ab.x); p[1] = f2bf(cd.y); *(us2*)&SH[A1B + (0 * TILE + nl) * A1S + f0] = p;
            p[0] = f2bf(ab.y); p[1] = f2bf(ef.x); *(us2*)&SH[A1B + (1 * TILE + nl) * A1S + f0] = p;
            p[0] = f2bf(cd.x); p[1] = f2bf(ef.y); *(us2*)&SH[A1B + (2 * TILE + nl) * A1S + f0] = p;
        }
        {
            us4 t0;
            t0[0] = f2bf(sreg.x); t0[1] = f2bf(sreg.y); t0[2] = f2bf(sreg.z); t0[3] = f2bf(sreg.w);
            *(us4*)&SH[A2B + srow * A2S + sf0] = t0;
        }
        asm volatile("s_waitcnt lgkmcnt(0)" ::: "memory");
        __builtin_amdgcn_s_barrier();                        // B1: A1+A2s ready; raw free

        // ---- issue asyncs + s load for t+NBLK (raw region now dead) ----
        if (t + NBLK < NT) {
            int t2 = t + NBLK;
            const float* vsrc = v + (size_t)t2 * TILE * 384;
            #pragma unroll
            for (int j = 0; j < 3; ++j) {
                int ofs = (w + j * 8) * 256;
                gload16(vsrc + ofs + lane * 4, &SH[RAWV + ofs * 2]);
            }
            sreg = *(const float4*)(s + (size_t)t2 * TILE * 128 + srow * 128 + sf0);
        }

        // ---- stage 1: Uv, Vv per-c passes; JIT weights (L2-hot) ----
        float nrm[4], inr[4];
        us4 pU[3];
        #pragma unroll
        for (int c = 0; c < 3; ++c) {
            f32x4 aU = (f32x4){0.f,0.f,0.f,0.f};
            f32x4 aV = (f32x4){0.f,0.f,0.f,0.f};
            #pragma unroll
            for (int ks = 0; ks < 4; ++ks) {
                int k0 = (ks << 5) + (kp << 3);
                bf16x8 bu, bv;
                if constexpr (PRE) {
                    bu = *(const bf16x8*)&wU[col * F + k0];
                    bv = *(const bf16x8*)&wV[col * F + k0];
                } else {
                    const float4* pu = (const float4*)&Uw[col * F + k0];
                    bu = pack8(pu[0], pu[1]);
                    const float4* pv = (const float4*)&Vw[col * F + k0];
                    bv = pack8(pv[0], pv[1]);
                }
                bf16x8 a = *(const bf16x8*)&SH[A1B + (c * TILE + l15) * A1S + k0];
                aU = __builtin_amdgcn_mfma_f32_16x16x32_bf16(a, bu, aU, 0, 0, 0);
                aV = __builtin_amdgcn_mfma_f32_16x16x32_bf16(a, bv, aV, 0, 0, 0);
            }
            us4 q;
            #pragma unroll
            for (int r = 0; r < 4; ++r) {
                float uu = aU[r], vv = aV[r];
                if (c == 0) { nrm[r] = vv * vv; inr[r] = uu * vv; }
                else        { nrm[r] += vv * vv; inr[r] += uu * vv; }
                q[r] = f2bf(uu);
            }
            pU[c] = q;
        }
        #pragma unroll
        for (int r = 0; r < 4; ++r) {
            int row = (kp << 2) + r;
            SH[A2B + row * A2S + 128 + col] = f2bf(nrm[r]);
        }
        asm volatile("s_waitcnt lgkmcnt(0)" ::: "memory");
        __builtin_amdgcn_s_barrier();                        // B2: A2 complete

        // ---- stage 2: h = shifted_softplus(mlp_in @ w1.T + b1) ----
        f32x4 accH = (f32x4){0.f,0.f,0.f,0.f};
        #pragma unroll
        for (int ks = 0; ks < 8; ++ks) {
            int k0 = (ks << 5) + (kp << 3);
            bf16x8 bw;
            if constexpr (PRE) {
                bw = *(const bf16x8*)&wW1[col * 256 + k0];
            } else {
                const float4* p = (const float4*)&aw1[col * 256 + k0];
                bw = pack8(p[0], p[1]);
            }
            bf16x8 a = *(const bf16x8*)&SH[A2B + l15 * A2S + k0];
            accH = __builtin_amdgcn_mfma_f32_16x16x32_bf16(a, bw, accH, 0, 0, 0);
        }
        #pragma unroll
        for (int r = 0; r < 4; ++r) {
            float x = accH[r] + b1;
            float hsp = fmaxf(x, 0.f) + __logf(1.f + __expf(-fabsf(x))) - 0.69314718056f;
            int row = (kp << 2) + r;
            SH[A3B + row * A3S + col] = f2bf(hsp);
        }
        asm volatile("s_waitcnt lgkmcnt(0)" ::: "memory");
        __builtin_amdgcn_s_barrier();                        // B3: A3 ready

        // ---- stage 3: three output GEMMs in one k-loop ----
        f32x4 accS = (f32x4){0.f,0.f,0.f,0.f};
        f32x4 accT = (f32x4){0.f,0.f,0.f,0.f};
        f32x4 accA = (f32x4){0.f,0.f,0.f,0.f};
        #pragma unroll
        for (int ks = 0; ks < 4; ++ks) {
            int k0 = (ks << 5) + (kp << 3);
            bf16x8 bws, bwt, bwv;
            if constexpr (PRE) {
                bws = *(const bf16x8*)&wW2[(0 * F + col) * F + k0];
                bwt = *(const bf16x8*)&wW2[(1 * F + col) * F + k0];
                bwv = *(const bf16x8*)&wW2[(2 * F + col) * F + k0];
            } else {
                const float4* p0 = (const float4*)&aw2[(size_t)(0 * F + col) * F + k0];
                const float4* p1 = (const float4*)&aw2[(size_t)(1 * F + col) * F + k0];
                const float4* p2 = (const float4*)&aw2[(size_t)(2 * F + col) * F + k0];
                bws = pack8(p0[0], p0[1]);
                bwt = pack8(p1[0], p1[1]);
                bwv = pack8(p2[0], p2[1]);
            }
            bf16x8 a = *(const bf16x8*)&SH[A3B + l15 * A3S + k0];
            accS = __builtin_amdgcn_mfma_f32_16x16x32_bf16(a, bws, accS, 0, 0, 0);
            accT = __builtin_amdgcn_mfma_f32_16x16x32_bf16(a, bwt, accT, 0, 0, 0);
            accA = __builtin_amdgcn_mfma_f32_16x16x32_bf16(a, bwv, accA, 0, 0, 0);
        }

        // ---- epilogue: v_new (dwordx3) and s_new; residuals from bf16 LDS ----
        #pragma unroll
        for (int r = 0; r < 4; ++r) {
            int nl = (kp << 2) + r;
            int n  = t * TILE + nl;
            float avv = accA[r] + bvv;
            size_t base = ((size_t)n * F + col) * 3;
            f3 val;
            val.x = bf2f(SH[A1B + (0 * TILE + nl) * A1S + col]) + avv * bf2f(pU[0][r]);
            val.y = bf2f(SH[A1B + (1 * TILE + nl) * A1S + col]) + avv * bf2f(pU[1][r]);
            val.z = bf2f(SH[A1B + (2 * TILE + nl) * A1S + col]) + avv * bf2f(pU[2][r]);
            *(f3*)&out[NF + base] = val;
            float sres = bf2f(SH[A2B + nl * A2S + col]);
            out[(size_t)n * F + col] = sres + (accS[r] + bss) + (accT[r] + bsv) * inr[r];
        }
    }
}

extern "C" void kernel_launch(void* const* d_in, const int* in_sizes, int n_in,
                              void* d_out, int out_size, void* d_ws, size_t ws_size,
                              hipStream_t stream) {
    (void)n_in; (void)out_size;
    const float* s   = (const float*)d_in[0];
    const float* v   = (const float*)d_in[1];
    const float* Uw  = (const float*)d_in[2];
    const float* Vw  = (const float*)d_in[3];
    const float* aw1 = (const float*)d_in[4];
    const float* ab1 = (const float*)d_in[5];
    const float* aw2 = (const float*)d_in[6];
    const float* ab2 = (const float*)d_in[7];
    float* out = (float*)d_out;
    int Ntot = in_sizes[0] / F;                 // 100000 (divisible by TILE=16)

    if (ws_size >= 114688u * sizeof(unsigned short)) {
        unsigned short* wbf = (unsigned short*)d_ws;
        hipLaunchKernelGGL(prep_w, dim3(112), dim3(256), 0, stream, Uw, Vw, aw1, aw2, wbf);
        hipLaunchKernelGGL((painn_main<true>), dim3(NBLK), dim3(NTHR), 0, stream,
                           s, v, Uw, Vw, aw1, ab1, aw2, ab2, wbf, out, Ntot);
    } else {
        hipLaunchKernelGGL((painn_main<false>), dim3(NBLK), dim3(NTHR), 0, stream,
                           s, v, Uw, Vw, aw1, ab1, aw2, ab2, (const unsigned short*)nullptr, out, Ntot);
    }
}